// Round 1
// baseline (566.309 us; speedup 1.0000x reference)
//
#include <hip/hip_runtime.h>
#include <hip/hip_bf16.h>

// C[M,N] = A[M,K] @ W[N,K]^T ; M=32768 (8*4096 tokens), N=K=2048. fp32 in/out.
// Strategy: on-the-fly fp32->bf16 (RNE) conversion + mfma_f32_16x16x32_bf16,
// 128x128 tile, BK=64, 4 waves (2x2 of 64x64), reg-staged LDS with XOR swizzle,
// XCD-aware block swizzle, n-fastest tile order for A-panel L2 reuse.

typedef __attribute__((ext_vector_type(8))) short bf16x8;
typedef __attribute__((ext_vector_type(4))) float f32x4;

#define M_DIM 32768
#define N_DIM 2048
#define K_DIM 2048
#define BM 128
#define BN 128
#define BK 64
#define NTILES (K_DIM / BK)          // 32
#define NBN (N_DIM / BN)             // 16
#define NWG ((M_DIM / BM) * NBN)     // 4096

__device__ __forceinline__ unsigned short f2bf(float f) {
    // fptrunc -> v_cvt_pk_bf16_f32 pairs (RNE); compiler handles packing.
    __bf16 b = (__bf16)f;
    return __builtin_bit_cast(unsigned short, b);
}

__global__ __launch_bounds__(256, 2)
void agmm_gemm(const float* __restrict__ A, const float* __restrict__ W,
               float* __restrict__ C) {
    // bf16 tiles, byte-addressed for XOR swizzle. 16 KiB each.
    __shared__ __attribute__((aligned(16))) char sA[BM * BK * 2];
    __shared__ __attribute__((aligned(16))) char sB[BN * BK * 2];

    const int tid  = threadIdx.x;
    const int lane = tid & 63;
    const int wid  = tid >> 6;   // 0..3
    const int wm   = wid >> 1;   // 0..1 -> 64-row half
    const int wn   = wid & 1;    // 0..1 -> 64-col half

    // Bijective XCD swizzle (NWG % 8 == 0): each XCD gets a contiguous range;
    // bn fastest so 16 consecutive blocks reuse one 1MB A-panel from L2.
    const int bid = blockIdx.x;
    const int swz = (bid & 7) * (NWG / 8) + (bid >> 3);
    const int bm  = swz >> 4;           // 0..255
    const int bn  = swz & (NBN - 1);    // 0..15

    // ---- staging assignment: 256 threads cover 128x64 fp32 tile in 8 passes.
    // thread -> (row = tid>>4 (+16/pass), 4 floats at col (tid&15)*4). Rows are
    // contiguous 256B per 16 threads -> coalesced dwordx4.
    const int srow = tid >> 4;            // 0..15
    const int scol = (tid & 15) << 2;     // float index 0..60

    const float* Ap = A + (size_t)(bm * BM + srow) * K_DIM + scol;
    const float* Wp = W + (size_t)(bn * BN + srow) * K_DIM + scol;

    // LDS write byte offset: row*128 + col*2, XOR-swizzled by (row&7)<<4.
    // (srow+16p)&7 == srow&7, so swizzle const across passes; pass stride 2048B.
    const int wbase = (srow * 128 + (scol << 1)) ^ ((srow & 7) << 4);

    // ---- fragment read constants (A and B frags load identically: NT layout)
    const int lrow = lane & 15;
    const int lkb  = (lane >> 4) << 3;        // k-offset 0,8,16,24 (bf16 elems)
    const int fxor = (lrow & 7) << 4;         // read-side swizzle (must match)
    const int arow0 = (wm * 64 + lrow) * 128; // byte row base in sA
    const int brow0 = (wn * 64 + lrow) * 128; // byte row base in sB

    f32x4 acc[4][4];
#pragma unroll
    for (int m = 0; m < 4; ++m)
#pragma unroll
        for (int n = 0; n < 4; ++n)
            acc[m][n] = (f32x4){0.f, 0.f, 0.f, 0.f};

    float4 areg[8], breg[8];

    // prologue: load tile 0 to regs
#pragma unroll
    for (int p = 0; p < 8; ++p) {
        areg[p] = *reinterpret_cast<const float4*>(Ap + (size_t)p * 16 * K_DIM);
        breg[p] = *reinterpret_cast<const float4*>(Wp + (size_t)p * 16 * K_DIM);
    }

    for (int kt = 0; kt < NTILES; ++kt) {
        __syncthreads();   // previous compute done reading LDS
        // convert + write current tile to LDS
#pragma unroll
        for (int p = 0; p < 8; ++p) {
            ushort av[4] = {f2bf(areg[p].x), f2bf(areg[p].y),
                            f2bf(areg[p].z), f2bf(areg[p].w)};
            *reinterpret_cast<ushort4*>(sA + (wbase + p * 2048)) =
                *reinterpret_cast<ushort4*>(av);
            ushort bv[4] = {f2bf(breg[p].x), f2bf(breg[p].y),
                            f2bf(breg[p].z), f2bf(breg[p].w)};
            *reinterpret_cast<ushort4*>(sB + (wbase + p * 2048)) =
                *reinterpret_cast<ushort4*>(bv);
        }
        __syncthreads();

        // issue next tile's global loads BEFORE compute (latency hides under MFMA)
        if (kt + 1 < NTILES) {
            const float* ap = Ap + (size_t)(kt + 1) * BK;
            const float* wp = Wp + (size_t)(kt + 1) * BK;
#pragma unroll
            for (int p = 0; p < 8; ++p) {
                areg[p] = *reinterpret_cast<const float4*>(ap + (size_t)p * 16 * K_DIM);
                breg[p] = *reinterpret_cast<const float4*>(wp + (size_t)p * 16 * K_DIM);
            }
        }

        // compute: 2 k-slices x 4m x 4n MFMAs
#pragma unroll
        for (int kk = 0; kk < 2; ++kk) {
            const int kcb = (kk * 32 + lkb) * 2;   // byte col offset
            bf16x8 af[4], bfr[4];
#pragma unroll
            for (int m = 0; m < 4; ++m)
                af[m] = *reinterpret_cast<const bf16x8*>(
                    sA + ((arow0 + m * 2048 + kcb) ^ fxor));
#pragma unroll
            for (int n = 0; n < 4; ++n)
                bfr[n] = *reinterpret_cast<const bf16x8*>(
                    sB + ((brow0 + n * 2048 + kcb) ^ fxor));
#pragma unroll
            for (int m = 0; m < 4; ++m)
#pragma unroll
                for (int n = 0; n < 4; ++n)
                    acc[m][n] = __builtin_amdgcn_mfma_f32_16x16x32_bf16(
                        af[m], bfr[n], acc[m][n], 0, 0, 0);
        }
    }

    // epilogue: C/D layout col=lane&15, row=(lane>>4)*4+reg (m89-verified)
    const size_t crow = (size_t)(bm * BM + wm * 64 + ((lane >> 4) << 2));
    const int    ccol = bn * BN + wn * 64 + (lane & 15);
    float* Cp = C + crow * N_DIM + ccol;
#pragma unroll
    for (int m = 0; m < 4; ++m)
#pragma unroll
        for (int j = 0; j < 4; ++j) {
            float* cr = Cp + (size_t)(m * 16 + j) * N_DIM;
#pragma unroll
            for (int n = 0; n < 4; ++n)
                cr[n * 16] = acc[m][n][j];
        }
}

extern "C" void kernel_launch(void* const* d_in, const int* in_sizes, int n_in,
                              void* d_out, int out_size, void* d_ws, size_t ws_size,
                              hipStream_t stream) {
    const float* A = (const float*)d_in[0];   // hidden_states [8,4096,2048] fp32
    const float* W = (const float*)d_in[1];   // weight [2048,2048] fp32
    float* C = (float*)d_out;                 // [32768,2048] fp32

    agmm_gemm<<<dim3(NWG), dim3(256), 0, stream>>>(A, W, C);
}

// Round 2
// 371.917 us; speedup vs baseline: 1.5227x; 1.5227x over previous
//
#include <hip/hip_runtime.h>
#include <hip/hip_bf16.h>

// C[M,N] = A[M,K] @ W[N,K]^T ; M=32768, N=K=2048. fp32 in/out.
// R2: pre-convert fp32->bf16 into d_ws (memory-bound pass), then m97-structure
// GEMM: 128x128 tile, BK=64, global_load_lds width-16 staging, XOR-swizzled LDS
// (swizzle applied via pre-swizzled GLOBAL source index + swizzled ds_read),
// 2 barriers/K-step, XCD-aware block swizzle, bn-fastest for A-panel L2 reuse.

typedef __attribute__((ext_vector_type(8))) short bf16x8;
typedef __attribute__((ext_vector_type(4))) float f32x4;

#define M_DIM 32768
#define N_DIM 2048
#define K_DIM 2048
#define BM 128
#define BN 128
#define BK 64
#define NTILES (K_DIM / BK)          // 32
#define NBN (N_DIM / BN)             // 16
#define NWG ((M_DIM / BM) * NBN)     // 4096

typedef __attribute__((address_space(3))) char lds_char;
typedef __attribute__((address_space(1))) char glb_char;

__device__ __forceinline__ unsigned short f2bf(float f) {
    __bf16 b = (__bf16)f;   // RNE, compiler emits v_cvt_pk_bf16_f32 pairs
    return __builtin_bit_cast(unsigned short, b);
}

// ---------------- fp32 -> bf16 convert (memory-bound, grid-stride) ----------
__global__ __launch_bounds__(256)
void cvt_f32_bf16(const float* __restrict__ src, ushort* __restrict__ dst, int n8) {
    const float4* s4 = (const float4*)src;
    int idx = blockIdx.x * blockDim.x + threadIdx.x;
    int stride = gridDim.x * blockDim.x;
    for (int i = idx; i < n8; i += stride) {
        float4 a = s4[2 * (size_t)i];
        float4 b = s4[2 * (size_t)i + 1];
        ushort r[8] = {f2bf(a.x), f2bf(a.y), f2bf(a.z), f2bf(a.w),
                       f2bf(b.x), f2bf(b.y), f2bf(b.z), f2bf(b.w)};
        *reinterpret_cast<uint4*>(dst + 8 * (size_t)i) =
            *reinterpret_cast<const uint4*>(r);
    }
}

// ---------------- bf16 GEMM, m97 structure ----------------------------------
__global__ __launch_bounds__(256, 4)
void agmm_bf16(const ushort* __restrict__ A, const ushort* __restrict__ W,
               float* __restrict__ C) {
    __shared__ __attribute__((aligned(16))) char sA[BM * BK * 2];  // 16 KiB
    __shared__ __attribute__((aligned(16))) char sB[BN * BK * 2];  // 16 KiB

    const int tid  = threadIdx.x;
    const int lane = tid & 63;
    const int w    = tid >> 6;   // 0..3
    const int wm   = w >> 1;     // 64-row half
    const int wn   = w & 1;      // 64-col half

    const int bid = blockIdx.x;
    const int swz = (bid & 7) * (NWG / 8) + (bid >> 3);  // bijective, NWG%8==0
    const int bm  = swz >> 4;
    const int bn  = swz & (NBN - 1);

    // -------- staging: global_load_lds writes LINEARLY (wave base + lane*16).
    // LDS byte o = (i*4+w)*1024 + lane*16 ; row = o>>7 = i*32 + w*8 + (lane>>3).
    // Logical col is pre-swizzled at the SOURCE: colb = (o&127) ^ ((row&7)<<4)
    // with row&7 == lane>>3  =>  col elems = ((lane&7) ^ (lane>>3)) * 8.
    const int lrow8 = lane >> 3;
    const int scol  = ((lane & 7) ^ lrow8) << 3;
    const ushort* Abase = A + (size_t)(bm * BM + w * 8 + lrow8) * K_DIM + scol;
    const ushort* Wbase = W + (size_t)(bn * BN + w * 8 + lrow8) * K_DIM + scol;

    // -------- fragment read constants (read-side swizzle matches source perm)
    const int lrow  = lane & 15;
    const int fxor  = (lrow & 7) << 4;         // row&7 == lrow&7 (offsets %8==0)
    const int lkb   = (lane >> 4) << 4;        // k byte offset within row
    const int arow0 = (wm * 64 + lrow) * 128;
    const int brow0 = (wn * 64 + lrow) * 128;

    f32x4 acc[4][4];
#pragma unroll
    for (int m = 0; m < 4; ++m)
#pragma unroll
        for (int n = 0; n < 4; ++n)
            acc[m][n] = (f32x4){0.f, 0.f, 0.f, 0.f};

    for (int kt = 0; kt < NTILES; ++kt) {
        const ushort* ak = Abase + kt * BK;
        const ushort* wk = Wbase + kt * BK;
#pragma unroll
        for (int i = 0; i < 4; ++i) {
            __builtin_amdgcn_global_load_lds(
                (const glb_char*)(ak + (size_t)i * 32 * K_DIM),
                (lds_char*)(sA + (i * 4 + w) * 1024), 16, 0, 0);
            __builtin_amdgcn_global_load_lds(
                (const glb_char*)(wk + (size_t)i * 32 * K_DIM),
                (lds_char*)(sB + (i * 4 + w) * 1024), 16, 0, 0);
        }
        __syncthreads();   // drains vmcnt(0): staged tile visible

#pragma unroll
        for (int kk = 0; kk < 2; ++kk) {
            const int kb = kk * 64 + lkb;      // logical col byte (0..112)
            bf16x8 af[4], bfr[4];
#pragma unroll
            for (int m = 0; m < 4; ++m)
                af[m] = *reinterpret_cast<const bf16x8*>(
                    sA + ((arow0 + m * 2048 + kb) ^ fxor));
#pragma unroll
            for (int n = 0; n < 4; ++n)
                bfr[n] = *reinterpret_cast<const bf16x8*>(
                    sB + ((brow0 + n * 2048 + kb) ^ fxor));
#pragma unroll
            for (int m = 0; m < 4; ++m)
#pragma unroll
                for (int n = 0; n < 4; ++n)
                    acc[m][n] = __builtin_amdgcn_mfma_f32_16x16x32_bf16(
                        af[m], bfr[n], acc[m][n], 0, 0, 0);
        }
        __syncthreads();   // all ds_reads done before next stage overwrites
    }

    // epilogue: C/D layout col=lane&15, row=(lane>>4)*4+reg (validated R1)
    const size_t crow = (size_t)(bm * BM + wm * 64 + ((lane >> 4) << 2));
    const int    ccol = bn * BN + wn * 64 + (lane & 15);
    float* Cp = C + crow * N_DIM + ccol;
#pragma unroll
    for (int m = 0; m < 4; ++m)
#pragma unroll
        for (int j = 0; j < 4; ++j) {
            float* cr = Cp + (size_t)(m * 16 + j) * N_DIM;
#pragma unroll
            for (int n = 0; n < 4; ++n)
                cr[n * 16] = acc[m][n][j];
        }
}

// ---------------- R1 fused fallback (if ws too small) ------------------------
__global__ __launch_bounds__(256, 2)
void agmm_fused(const float* __restrict__ A, const float* __restrict__ W,
                float* __restrict__ C) {
    __shared__ __attribute__((aligned(16))) char sA[BM * BK * 2];
    __shared__ __attribute__((aligned(16))) char sB[BN * BK * 2];

    const int tid  = threadIdx.x;
    const int lane = tid & 63;
    const int wid  = tid >> 6;
    const int wm   = wid >> 1;
    const int wn   = wid & 1;

    const int bid = blockIdx.x;
    const int swz = (bid & 7) * (NWG / 8) + (bid >> 3);
    const int bm  = swz >> 4;
    const int bn  = swz & (NBN - 1);

    const int srow = tid >> 4;
    const int scol = (tid & 15) << 2;

    const float* Ap = A + (size_t)(bm * BM + srow) * K_DIM + scol;
    const float* Wp = W + (size_t)(bn * BN + srow) * K_DIM + scol;
    const int wbase = (srow * 128 + (scol << 1)) ^ ((srow & 7) << 4);

    const int lrow = lane & 15;
    const int lkb  = (lane >> 4) << 3;
    const int fxor = (lrow & 7) << 4;
    const int arow0 = (wm * 64 + lrow) * 128;
    const int brow0 = (wn * 64 + lrow) * 128;

    f32x4 acc[4][4];
#pragma unroll
    for (int m = 0; m < 4; ++m)
#pragma unroll
        for (int n = 0; n < 4; ++n)
            acc[m][n] = (f32x4){0.f, 0.f, 0.f, 0.f};

    float4 areg[8], breg[8];
#pragma unroll
    for (int p = 0; p < 8; ++p) {
        areg[p] = *reinterpret_cast<const float4*>(Ap + (size_t)p * 16 * K_DIM);
        breg[p] = *reinterpret_cast<const float4*>(Wp + (size_t)p * 16 * K_DIM);
    }

    for (int kt = 0; kt < NTILES; ++kt) {
        __syncthreads();
#pragma unroll
        for (int p = 0; p < 8; ++p) {
            ushort av[4] = {f2bf(areg[p].x), f2bf(areg[p].y),
                            f2bf(areg[p].z), f2bf(areg[p].w)};
            *reinterpret_cast<ushort4*>(sA + (wbase + p * 2048)) =
                *reinterpret_cast<ushort4*>(av);
            ushort bv[4] = {f2bf(breg[p].x), f2bf(breg[p].y),
                            f2bf(breg[p].z), f2bf(breg[p].w)};
            *reinterpret_cast<ushort4*>(sB + (wbase + p * 2048)) =
                *reinterpret_cast<ushort4*>(bv);
        }
        __syncthreads();

        if (kt + 1 < NTILES) {
            const float* ap = Ap + (size_t)(kt + 1) * BK;
            const float* wp = Wp + (size_t)(kt + 1) * BK;
#pragma unroll
            for (int p = 0; p < 8; ++p) {
                areg[p] = *reinterpret_cast<const float4*>(ap + (size_t)p * 16 * K_DIM);
                breg[p] = *reinterpret_cast<const float4*>(wp + (size_t)p * 16 * K_DIM);
            }
        }

#pragma unroll
        for (int kk = 0; kk < 2; ++kk) {
            const int kcb = (kk * 32 + lkb) * 2;
            bf16x8 af[4], bfr[4];
#pragma unroll
            for (int m = 0; m < 4; ++m)
                af[m] = *reinterpret_cast<const bf16x8*>(
                    sA + ((arow0 + m * 2048 + kcb) ^ fxor));
#pragma unroll
            for (int n = 0; n < 4; ++n)
                bfr[n] = *reinterpret_cast<const bf16x8*>(
                    sB + ((brow0 + n * 2048 + kcb) ^ fxor));
#pragma unroll
            for (int m = 0; m < 4; ++m)
#pragma unroll
                for (int n = 0; n < 4; ++n)
                    acc[m][n] = __builtin_amdgcn_mfma_f32_16x16x32_bf16(
                        af[m], bfr[n], acc[m][n], 0, 0, 0);
        }
    }

    const size_t crow = (size_t)(bm * BM + wm * 64 + ((lane >> 4) << 2));
    const int    ccol = bn * BN + wn * 64 + (lane & 15);
    float* Cp = C + crow * N_DIM + ccol;
#pragma unroll
    for (int m = 0; m < 4; ++m)
#pragma unroll
        for (int j = 0; j < 4; ++j) {
            float* cr = Cp + (size_t)(m * 16 + j) * N_DIM;
#pragma unroll
            for (int n = 0; n < 4; ++n)
                cr[n * 16] = acc[m][n][j];
        }
}

extern "C" void kernel_launch(void* const* d_in, const int* in_sizes, int n_in,
                              void* d_out, int out_size, void* d_ws, size_t ws_size,
                              hipStream_t stream) {
    const float* A  = (const float*)d_in[0];   // [8,4096,2048] fp32
    const float* Wt = (const float*)d_in[1];   // [2048,2048] fp32
    float* C = (float*)d_out;                  // [32768,2048] fp32

    const size_t needA = (size_t)M_DIM * K_DIM * 2;
    const size_t needW = (size_t)N_DIM * K_DIM * 2;

    if (ws_size >= needA + needW) {
        ushort* Abf = (ushort*)d_ws;
        ushort* Wbf = (ushort*)((char*)d_ws + needA);
        cvt_f32_bf16<<<dim3(2048), dim3(256), 0, stream>>>(A, Abf, (M_DIM * K_DIM) / 8);
        cvt_f32_bf16<<<dim3(2048), dim3(256), 0, stream>>>(Wt, Wbf, (N_DIM * K_DIM) / 8);
        agmm_bf16<<<dim3(NWG), dim3(256), 0, stream>>>(Abf, Wbf, C);
    } else {
        agmm_fused<<<dim3(NWG), dim3(256), 0, stream>>>(A, Wt, C);
    }
}

// Round 3
// 337.955 us; speedup vs baseline: 1.6757x; 1.1005x over previous
//
#include <hip/hip_runtime.h>
#include <hip/hip_bf16.h>

// C[M,N] = A[M,K] @ W[N,K]^T ; M=32768, N=K=2048. fp32 in/out.
// R3: pre-convert fp32->bf16 into d_ws, then 256x256-tile 8-wave deep-pipelined
// GEMM (T2 swizzle + T3 4-phase/K-tile + T4 counted vmcnt + T5 setprio).
// Pipeline ledger (per wave, 2 gload_lds per phase, stage tile t+1 during t):
//   issue order: P0:B0x2  P1:B1x2  P2:Aq0,Aq1  P3:Aq2,Aq3
//   consume:     P(t,0): B0,B1,Aq0   P(t,1): Aq1   P(t,2): Aq2   P(t,3): Aq3
//   end-of-phase gates (outstanding -> needed): P0:5->vmcnt(4) P1:6->vmcnt(5)
//   P2:7->vmcnt(6) P3:8->vmcnt(3). Last tile peeled with drain gates 2/1/0/0.

typedef __attribute__((ext_vector_type(8))) short bf16x8;
typedef __attribute__((ext_vector_type(4))) float f32x4;

#define M_DIM 32768
#define N_DIM 2048
#define K_DIM 2048
#define BM 256
#define BN 256
#define BK 64
#define NT (K_DIM / BK)              // 32
#define NBN (N_DIM / BN)             // 8
#define NWG ((M_DIM / BM) * NBN)     // 1024

typedef __attribute__((address_space(3))) char lds_char;
typedef __attribute__((address_space(1))) char glb_char;

__device__ __forceinline__ unsigned short f2bf(float f) {
    __bf16 b = (__bf16)f;   // RNE
    return __builtin_bit_cast(unsigned short, b);
}

// ---------------- fp32 -> bf16 convert (memory-bound, grid-stride) ----------
__global__ __launch_bounds__(256)
void cvt_f32_bf16(const float* __restrict__ src, ushort* __restrict__ dst, int n8) {
    const float4* s4 = (const float4*)src;
    int idx = blockIdx.x * blockDim.x + threadIdx.x;
    int stride = gridDim.x * blockDim.x;
    for (int i = idx; i < n8; i += stride) {
        float4 a = s4[2 * (size_t)i];
        float4 b = s4[2 * (size_t)i + 1];
        ushort r[8] = {f2bf(a.x), f2bf(a.y), f2bf(a.z), f2bf(a.w),
                       f2bf(b.x), f2bf(b.y), f2bf(b.z), f2bf(b.w)};
        *reinterpret_cast<uint4*>(dst + 8 * (size_t)i) =
            *reinterpret_cast<const uint4*>(r);
    }
}

// ---------------- 256^2 8-wave deep-pipelined bf16 GEMM ---------------------
__global__ __launch_bounds__(512, 2)
void agmm_8phase(const ushort* __restrict__ A, const ushort* __restrict__ W,
                 float* __restrict__ C) {
    // sA[buf]: buf*32768        (256 rows x 64 cols bf16, row stride 128B)
    // sB[buf]: 65536 + buf*32768
    __shared__ __attribute__((aligned(16))) char sm[131072];

    const int tid  = threadIdx.x;
    const int lane = tid & 63;
    const int w    = tid >> 6;      // 0..7
    const int wm   = w >> 2;        // 0..1 -> 128-row half
    const int wn   = w & 3;         // 0..3 -> 64-col slice

    const int bid = blockIdx.x;
    const int swz = (bid & 7) * (NWG / 8) + (bid >> 3);  // bijective (NWG%8==0)
    const int bm  = swz >> 3;            // 0..127
    const int bn  = swz & (NBN - 1);     // 0..7

    // staging source pre-swizzle (linear LDS dest; read-side applies same XOR)
    const int lsub = lane >> 3;                       // 0..7 (= row&7 at dest)
    const int scol = ((lane & 7) ^ lsub) << 3;        // pre-swizzled col elems

    const ushort* Abase = A + (size_t)bm * BM * K_DIM + scol;
    const ushort* Wbase = W + (size_t)bn * BN * K_DIM + scol;

    const int aqrow = wm * 128 + wn * 8;  // this wave's A-quarter row base

    // fragment read constants
    const int lrow = lane & 15;
    const int fxor = (lrow & 7) << 4;
    const int kcb0 = (lane >> 4) << 4;    // 0,16,32,48 byte k-offset

    f32x4 acc[8][4];
#pragma unroll
    for (int m = 0; m < 8; ++m)
#pragma unroll
        for (int n = 0; n < 4; ++n)
            acc[m][n] = (f32x4){0.f, 0.f, 0.f, 0.f};
    bf16x8 bfr[4][2];   // B-frags, loaded at phase 0, live for the K-tile

#define GLD16(SRC, LOFF)                                                       \
    __builtin_amdgcn_global_load_lds((const glb_char*)(SRC),                   \
                                     (lds_char*)(sm + (LOFF)), 16, 0, 0)
    // B half H (128 rows): wave stages rows H*128 + w*16 .. +15 (2 loads)
#define STAGE_B(KT, H, BUF) do {                                               \
        const int rb_ = (H) * 128 + (w << 4);                                  \
        GLD16(Wbase + (size_t)(rb_ + lsub) * K_DIM + (KT) * BK,                \
              65536 + (BUF) * 32768 + rb_ * 128);                              \
        GLD16(Wbase + (size_t)(rb_ + 8 + lsub) * K_DIM + (KT) * BK,            \
              65536 + (BUF) * 32768 + (rb_ + 8) * 128);                        \
    } while (0)
    // A quarter QK: rows {wm*128 + QK*32 + wn*8 .. +7} per wave (1 load)
#define STAGE_AQ(KT, QK, BUF) do {                                             \
        const int ra_ = aqrow + (QK) * 32;                                     \
        GLD16(Abase + (size_t)(ra_ + lsub) * K_DIM + (KT) * BK,                \
              (BUF) * 32768 + ra_ * 128);                                      \
    } while (0)

    // prologue: tile 0 -> buf 0 ; issue order B0a,B0b,B1a,B1b,A0,A1,A2,A3
    STAGE_B(0, 0, 0);
    STAGE_B(0, 1, 0);
    STAGE_AQ(0, 0, 0); STAGE_AQ(0, 1, 0); STAGE_AQ(0, 2, 0); STAGE_AQ(0, 3, 0);
    asm volatile("s_waitcnt vmcnt(3)" ::: "memory");   // B0,B1,Aq0 done
    __builtin_amdgcn_s_barrier();

    // phase: ds_read(frags for Q) | stage-issue | barrier | lgkm0 | 16 MFMA |
    //        vmcnt gate (covers NEXT phase's reads) | barrier
#define PHASE(Q, LOADB, GATE, STAGE_CODE) do {                                 \
        bf16x8 af_[2][2];                                                      \
        _Pragma("unroll") for (int m2 = 0; m2 < 2; ++m2)                       \
        _Pragma("unroll") for (int kk = 0; kk < 2; ++kk)                       \
            af_[m2][kk] = *(const bf16x8*)(sm + abase +                        \
                ((Q) * 32 + m2 * 16) * 128 + ((kk * 64 + kcb0) ^ fxor));       \
        if (LOADB) {                                                           \
            _Pragma("unroll") for (int n = 0; n < 4; ++n)                      \
            _Pragma("unroll") for (int kk = 0; kk < 2; ++kk)                   \
                bfr[n][kk] = *(const bf16x8*)(sm + bbase +                     \
                    (n * 16) * 128 + ((kk * 64 + kcb0) ^ fxor));               \
        }                                                                      \
        STAGE_CODE;                                                            \
        __builtin_amdgcn_s_barrier();                                          \
        asm volatile("s_waitcnt lgkmcnt(0)" ::: "memory");                     \
        __builtin_amdgcn_sched_barrier(0);                                     \
        __builtin_amdgcn_s_setprio(1);                                         \
        _Pragma("unroll") for (int m2 = 0; m2 < 2; ++m2)                       \
        _Pragma("unroll") for (int n = 0; n < 4; ++n)                          \
        _Pragma("unroll") for (int kk = 0; kk < 2; ++kk)                       \
            acc[(Q) * 2 + m2][n] = __builtin_amdgcn_mfma_f32_16x16x32_bf16(    \
                af_[m2][kk], bfr[n][kk], acc[(Q) * 2 + m2][n], 0, 0, 0);       \
        __builtin_amdgcn_s_setprio(0);                                         \
        asm volatile("s_waitcnt " GATE ::: "memory");                          \
        __builtin_amdgcn_s_barrier();                                          \
    } while (0)

    for (int t = 0; t < NT - 1; ++t) {
        const int cur = t & 1, nxt = cur ^ 1;
        const int abase = cur * 32768 + (wm * 128 + lrow) * 128;
        const int bbase = 65536 + cur * 32768 + (wn * 64 + lrow) * 128;
        PHASE(0, 1, "vmcnt(4)", { STAGE_B(t + 1, 0, nxt); });
        PHASE(1, 0, "vmcnt(5)", { STAGE_B(t + 1, 1, nxt); });
        PHASE(2, 0, "vmcnt(6)", { STAGE_AQ(t + 1, 0, nxt); STAGE_AQ(t + 1, 1, nxt); });
        PHASE(3, 0, "vmcnt(3)", { STAGE_AQ(t + 1, 2, nxt); STAGE_AQ(t + 1, 3, nxt); });
    }
    {   // last K-tile: no staging, drain gates
        const int cur = (NT - 1) & 1;
        const int abase = cur * 32768 + (wm * 128 + lrow) * 128;
        const int bbase = 65536 + cur * 32768 + (wn * 64 + lrow) * 128;
        PHASE(0, 1, "vmcnt(2)", {});
        PHASE(1, 0, "vmcnt(1)", {});
        PHASE(2, 0, "vmcnt(0)", {});
        PHASE(3, 0, "vmcnt(0)", {});
    }
#undef PHASE
#undef STAGE_AQ
#undef STAGE_B
#undef GLD16

    // epilogue: C/D layout col=lane&15, row=(lane>>4)*4+reg (R1/R2-validated)
    const size_t crow = (size_t)(bm * BM + wm * 128 + ((lane >> 4) << 2));
    const int    ccol = bn * BN + wn * 64 + (lane & 15);
    float* Cp = C + crow * N_DIM + ccol;
#pragma unroll
    for (int m = 0; m < 8; ++m)
#pragma unroll
        for (int j = 0; j < 4; ++j) {
            float* cr = Cp + (size_t)(m * 16 + j) * N_DIM;
#pragma unroll
            for (int n = 0; n < 4; ++n)
                cr[n * 16] = acc[m][n][j];
        }
}

// ---------------- fused fp32 fallback (ws too small; R1-validated) ----------
__global__ __launch_bounds__(256, 2)
void agmm_fused(const float* __restrict__ A, const float* __restrict__ W,
                float* __restrict__ C) {
    __shared__ __attribute__((aligned(16))) char sA[128 * 64 * 2];
    __shared__ __attribute__((aligned(16))) char sB[128 * 64 * 2];

    const int tid  = threadIdx.x;
    const int lane = tid & 63;
    const int wid  = tid >> 6;
    const int wm   = wid >> 1;
    const int wn   = wid & 1;

    const int nwg = (M_DIM / 128) * (N_DIM / 128);
    const int bid = blockIdx.x;
    const int swz = (bid & 7) * (nwg / 8) + (bid >> 3);
    const int bm  = swz >> 4;
    const int bn  = swz & 15;

    const int srow = tid >> 4;
    const int scol = (tid & 15) << 2;

    const float* Ap = A + (size_t)(bm * 128 + srow) * K_DIM + scol;
    const float* Wp = W + (size_t)(bn * 128 + srow) * K_DIM + scol;
    const int wbase = (srow * 128 + (scol << 1)) ^ ((srow & 7) << 4);

    const int lrow = lane & 15;
    const int lkb  = (lane >> 4) << 3;
    const int fxor = (lrow & 7) << 4;
    const int arow0 = (wm * 64 + lrow) * 128;
    const int brow0 = (wn * 64 + lrow) * 128;

    f32x4 acc[4][4];
#pragma unroll
    for (int m = 0; m < 4; ++m)
#pragma unroll
        for (int n = 0; n < 4; ++n)
            acc[m][n] = (f32x4){0.f, 0.f, 0.f, 0.f};

    float4 areg[8], breg[8];
#pragma unroll
    for (int p = 0; p < 8; ++p) {
        areg[p] = *reinterpret_cast<const float4*>(Ap + (size_t)p * 16 * K_DIM);
        breg[p] = *reinterpret_cast<const float4*>(Wp + (size_t)p * 16 * K_DIM);
    }

    for (int kt = 0; kt < NT; ++kt) {
        __syncthreads();
#pragma unroll
        for (int p = 0; p < 8; ++p) {
            ushort av[4] = {f2bf(areg[p].x), f2bf(areg[p].y),
                            f2bf(areg[p].z), f2bf(areg[p].w)};
            *reinterpret_cast<ushort4*>(sA + (wbase + p * 2048)) =
                *reinterpret_cast<ushort4*>(av);
            ushort bv[4] = {f2bf(breg[p].x), f2bf(breg[p].y),
                            f2bf(breg[p].z), f2bf(breg[p].w)};
            *reinterpret_cast<ushort4*>(sB + (wbase + p * 2048)) =
                *reinterpret_cast<ushort4*>(bv);
        }
        __syncthreads();

        if (kt + 1 < NT) {
            const float* ap = Ap + (size_t)(kt + 1) * BK;
            const float* wp = Wp + (size_t)(kt + 1) * BK;
#pragma unroll
            for (int p = 0; p < 8; ++p) {
                areg[p] = *reinterpret_cast<const float4*>(ap + (size_t)p * 16 * K_DIM);
                breg[p] = *reinterpret_cast<const float4*>(wp + (size_t)p * 16 * K_DIM);
            }
        }

#pragma unroll
        for (int kk = 0; kk < 2; ++kk) {
            const int kcb = (kk * 32 + lkb) * 2;
            bf16x8 af[4], bfv[4];
#pragma unroll
            for (int m = 0; m < 4; ++m)
                af[m] = *reinterpret_cast<const bf16x8*>(
                    sA + ((arow0 + m * 2048 + kcb) ^ fxor));
#pragma unroll
            for (int n = 0; n < 4; ++n)
                bfv[n] = *reinterpret_cast<const bf16x8*>(
                    sB + ((brow0 + n * 2048 + kcb) ^ fxor));
#pragma unroll
            for (int m = 0; m < 4; ++m)
#pragma unroll
                for (int n = 0; n < 4; ++n)
                    acc[m][n] = __builtin_amdgcn_mfma_f32_16x16x32_bf16(
                        af[m], bfv[n], acc[m][n], 0, 0, 0);
        }
    }

    const size_t crow = (size_t)(bm * 128 + wm * 64 + ((lane >> 4) << 2));
    const int    ccol = bn * 128 + wn * 64 + (lane & 15);
    float* Cp = C + crow * N_DIM + ccol;
#pragma unroll
    for (int m = 0; m < 4; ++m)
#pragma unroll
        for (int j = 0; j < 4; ++j) {
            float* cr = Cp + (size_t)(m * 16 + j) * N_DIM;
#pragma unroll
            for (int n = 0; n < 4; ++n)
                cr[n * 16] = acc[m][n][j];
        }
}

extern "C" void kernel_launch(void* const* d_in, const int* in_sizes, int n_in,
                              void* d_out, int out_size, void* d_ws, size_t ws_size,
                              hipStream_t stream) {
    const float* A  = (const float*)d_in[0];   // [8,4096,2048] fp32
    const float* Wt = (const float*)d_in[1];   // [2048,2048] fp32
    float* C = (float*)d_out;                  // [32768,2048] fp32

    const size_t needA = (size_t)M_DIM * K_DIM * 2;
    const size_t needW = (size_t)N_DIM * K_DIM * 2;

    if (ws_size >= needA + needW) {
        ushort* Abf = (ushort*)d_ws;
        ushort* Wbf = (ushort*)((char*)d_ws + needA);
        cvt_f32_bf16<<<dim3(2048), dim3(256), 0, stream>>>(A, Abf, (M_DIM * K_DIM) / 8);
        cvt_f32_bf16<<<dim3(2048), dim3(256), 0, stream>>>(Wt, Wbf, (N_DIM * K_DIM) / 8);
        agmm_8phase<<<dim3(NWG), dim3(512), 0, stream>>>(Abf, Wbf, C);
    } else {
        agmm_fused<<<dim3((M_DIM / 128) * (N_DIM / 128)), dim3(256), 0, stream>>>(A, Wt, C);
    }
}

// Round 4
// 330.669 us; speedup vs baseline: 1.7126x; 1.0220x over previous
//
#include <hip/hip_runtime.h>
#include <hip/hip_bf16.h>

// C[M,N] = A[M,K] @ W[N,K]^T ; M=32768, N=K=2048. fp32 in/out.
// R4: pre-convert fp32->bf16 into d_ws, then 256x256-tile 8-wave pipelined GEMM.
// vs R3: ONE barrier per phase (4/K-tile), no lgkm full-drain, no mid-phase
// sched pin (compiler emits fine-grained lgkm waits for IR-level ds_reads);
// sched_barrier(0) only AFTER each s_barrier (blocks hoisting across the
// cross-wave publish point). Issue rebalanced 3/3/2/0 -> min slack 3 phases.
// Per-wave vmcnt ledger (issue order #1 B0a,#2 B0b,#3 Aq0,#4 B1a,#5 B1b,
// #6 Aq1,#7 Aq2,#8 Aq3; consume P0:{B0,B1,Aq0} P1:Aq1 P2:Aq2 P3:Aq3):
//   steady gates  P0:vmcnt(5)  P1:vmcnt(7)  P2:vmcnt(8)  P3:vmcnt(3)
//   last tile     P0:vmcnt(2)  P1:vmcnt(1)  P2:vmcnt(0)  P3:vmcnt(0)

typedef __attribute__((ext_vector_type(8))) short bf16x8;
typedef __attribute__((ext_vector_type(4))) float f32x4;

#define M_DIM 32768
#define N_DIM 2048
#define K_DIM 2048
#define BM 256
#define BN 256
#define BK 64
#define NT (K_DIM / BK)              // 32
#define NBN (N_DIM / BN)             // 8
#define NWG ((M_DIM / BM) * NBN)     // 1024

typedef __attribute__((address_space(3))) char lds_char;
typedef __attribute__((address_space(1))) char glb_char;

__device__ __forceinline__ unsigned short f2bf(float f) {
    __bf16 b = (__bf16)f;   // RNE
    return __builtin_bit_cast(unsigned short, b);
}

// ---------------- fp32 -> bf16 convert (memory-bound, grid-stride) ----------
__global__ __launch_bounds__(256)
void cvt_f32_bf16(const float* __restrict__ src, ushort* __restrict__ dst, int n8) {
    const float4* s4 = (const float4*)src;
    int idx = blockIdx.x * blockDim.x + threadIdx.x;
    int stride = gridDim.x * blockDim.x;
    for (int i = idx; i < n8; i += stride) {
        float4 a = s4[2 * (size_t)i];
        float4 b = s4[2 * (size_t)i + 1];
        ushort r[8] = {f2bf(a.x), f2bf(a.y), f2bf(a.z), f2bf(a.w),
                       f2bf(b.x), f2bf(b.y), f2bf(b.z), f2bf(b.w)};
        *reinterpret_cast<uint4*>(dst + 8 * (size_t)i) =
            *reinterpret_cast<const uint4*>(r);
    }
}

// ---------------- 256^2 8-wave pipelined bf16 GEMM ---------------------------
__global__ __launch_bounds__(512, 2)
void agmm_8phase(const ushort* __restrict__ A, const ushort* __restrict__ W,
                 float* __restrict__ C) {
    // sA[buf]: buf*32768 ; sB[buf]: 65536 + buf*32768 (256r x 64c bf16, 128B rows)
    __shared__ __attribute__((aligned(16))) char sm[131072];

    const int tid  = threadIdx.x;
    const int lane = tid & 63;
    const int w    = tid >> 6;      // 0..7
    const int wm   = w >> 2;        // 0..1 -> 128-row half
    const int wn   = w & 3;         // 0..3 -> 64-col slice

    const int bid = blockIdx.x;
    const int swz = (bid & 7) * (NWG / 8) + (bid >> 3);  // bijective (NWG%8==0)
    const int bm  = swz >> 3;            // 0..127
    const int bn  = swz & (NBN - 1);     // 0..7

    // staging source pre-swizzle (linear LDS dest; read applies same XOR)
    const int lsub = lane >> 3;                       // row&7 at dest
    const int scol = ((lane & 7) ^ lsub) << 3;        // pre-swizzled col elems

    const ushort* Abase = A + (size_t)bm * BM * K_DIM + scol;
    const ushort* Wbase = W + (size_t)bn * BN * K_DIM + scol;

    const int aqrow = wm * 128 + wn * 8;  // this wave's A-quarter row base

    const int lrow = lane & 15;
    const int fxor = (lrow & 7) << 4;
    const int kcb0 = (lane >> 4) << 4;    // 0,16,32,48 byte k-offset

    f32x4 acc[8][4];
#pragma unroll
    for (int m = 0; m < 8; ++m)
#pragma unroll
        for (int n = 0; n < 4; ++n)
            acc[m][n] = (f32x4){0.f, 0.f, 0.f, 0.f};
    bf16x8 bfr[4][2];   // B-frags, loaded at phase 0, live for the K-tile

#define GLD16(SRC, LOFF)                                                       \
    __builtin_amdgcn_global_load_lds((const glb_char*)(SRC),                   \
                                     (lds_char*)(sm + (LOFF)), 16, 0, 0)
#define STAGE_B(KT, H, BUF) do {                                               \
        const int rb_ = (H) * 128 + (w << 4);                                  \
        GLD16(Wbase + (size_t)(rb_ + lsub) * K_DIM + (KT) * BK,                \
              65536 + (BUF) * 32768 + rb_ * 128);                              \
        GLD16(Wbase + (size_t)(rb_ + 8 + lsub) * K_DIM + (KT) * BK,            \
              65536 + (BUF) * 32768 + (rb_ + 8) * 128);                        \
    } while (0)
#define STAGE_AQ(KT, QK, BUF) do {                                             \
        const int ra_ = aqrow + (QK) * 32;                                     \
        GLD16(Abase + (size_t)(ra_ + lsub) * K_DIM + (KT) * BK,                \
              (BUF) * 32768 + ra_ * 128);                                      \
    } while (0)

    // prologue: tile 0 -> buf 0, issue order matches steady-state ledger
    STAGE_B(0, 0, 0); STAGE_AQ(0, 0, 0);
    STAGE_B(0, 1, 0); STAGE_AQ(0, 1, 0);
    STAGE_AQ(0, 2, 0); STAGE_AQ(0, 3, 0);
    asm volatile("s_waitcnt vmcnt(3)" ::: "memory");   // B0,B1,Aq0 landed
    __builtin_amdgcn_s_barrier();
    __builtin_amdgcn_sched_barrier(0);

    // phase: [ds_read frags][stage-issue][setprio1 MFMA x16 setprio0]
    //        [vmcnt gate][s_barrier][sched_barrier(0)]
#define PHASE(Q, LOADB, GATE, STAGE_CODE) do {                                 \
        bf16x8 af_[2][2];                                                      \
        _Pragma("unroll") for (int m2 = 0; m2 < 2; ++m2)                       \
        _Pragma("unroll") for (int kk = 0; kk < 2; ++kk)                       \
            af_[m2][kk] = *(const bf16x8*)(sm + abase +                        \
                ((Q) * 32 + m2 * 16) * 128 + ((kk * 64 + kcb0) ^ fxor));       \
        if (LOADB) {                                                           \
            _Pragma("unroll") for (int n = 0; n < 4; ++n)                      \
            _Pragma("unroll") for (int kk = 0; kk < 2; ++kk)                   \
                bfr[n][kk] = *(const bf16x8*)(sm + bbase +                     \
                    (n * 16) * 128 + ((kk * 64 + kcb0) ^ fxor));               \
        }                                                                      \
        STAGE_CODE;                                                            \
        __builtin_amdgcn_s_setprio(1);                                         \
        _Pragma("unroll") for (int m2 = 0; m2 < 2; ++m2)                       \
        _Pragma("unroll") for (int n = 0; n < 4; ++n)                          \
        _Pragma("unroll") for (int kk = 0; kk < 2; ++kk)                       \
            acc[(Q) * 2 + m2][n] = __builtin_amdgcn_mfma_f32_16x16x32_bf16(    \
                af_[m2][kk], bfr[n][kk], acc[(Q) * 2 + m2][n], 0, 0, 0);       \
        __builtin_amdgcn_s_setprio(0);                                         \
        asm volatile("s_waitcnt " GATE ::: "memory");                          \
        __builtin_amdgcn_s_barrier();                                          \
        __builtin_amdgcn_sched_barrier(0);                                     \
    } while (0)

    for (int t = 0; t < NT - 1; ++t) {
        const int cur = t & 1, nxt = cur ^ 1;
        const int abase = cur * 32768 + (wm * 128 + lrow) * 128;
        const int bbase = 65536 + cur * 32768 + (wn * 64 + lrow) * 128;
        PHASE(0, 1, "vmcnt(5)", { STAGE_B(t + 1, 0, nxt); STAGE_AQ(t + 1, 0, nxt); });
        PHASE(1, 0, "vmcnt(7)", { STAGE_B(t + 1, 1, nxt); STAGE_AQ(t + 1, 1, nxt); });
        PHASE(2, 0, "vmcnt(8)", { STAGE_AQ(t + 1, 2, nxt); STAGE_AQ(t + 1, 3, nxt); });
        PHASE(3, 0, "vmcnt(3)", {});
    }
    {   // last K-tile: no staging, drain gates
        const int cur = (NT - 1) & 1;
        const int abase = cur * 32768 + (wm * 128 + lrow) * 128;
        const int bbase = 65536 + cur * 32768 + (wn * 64 + lrow) * 128;
        PHASE(0, 1, "vmcnt(2)", {});
        PHASE(1, 0, "vmcnt(1)", {});
        PHASE(2, 0, "vmcnt(0)", {});
        PHASE(3, 0, "vmcnt(0)", {});
    }
#undef PHASE
#undef STAGE_AQ
#undef STAGE_B
#undef GLD16

    // epilogue: C/D layout col=lane&15, row=(lane>>4)*4+reg (R1-R3 validated)
    const size_t crow = (size_t)(bm * BM + wm * 128 + ((lane >> 4) << 2));
    const int    ccol = bn * BN + wn * 64 + (lane & 15);
    float* Cp = C + crow * N_DIM + ccol;
#pragma unroll
    for (int m = 0; m < 8; ++m)
#pragma unroll
        for (int j = 0; j < 4; ++j) {
            float* cr = Cp + (size_t)(m * 16 + j) * N_DIM;
#pragma unroll
            for (int n = 0; n < 4; ++n)
                cr[n * 16] = acc[m][n][j];
        }
}

// ---------------- fused fp32 fallback (ws too small; R1-validated) ----------
__global__ __launch_bounds__(256, 2)
void agmm_fused(const float* __restrict__ A, const float* __restrict__ W,
                float* __restrict__ C) {
    __shared__ __attribute__((aligned(16))) char sA[128 * 64 * 2];
    __shared__ __attribute__((aligned(16))) char sB[128 * 64 * 2];

    const int tid  = threadIdx.x;
    const int lane = tid & 63;
    const int wid  = tid >> 6;
    const int wm   = wid >> 1;
    const int wn   = wid & 1;

    const int nwg = (M_DIM / 128) * (N_DIM / 128);
    const int bid = blockIdx.x;
    const int swz = (bid & 7) * (nwg / 8) + (bid >> 3);
    const int bm  = swz >> 4;
    const int bn  = swz & 15;

    const int srow = tid >> 4;
    const int scol = (tid & 15) << 2;

    const float* Ap = A + (size_t)(bm * 128 + srow) * K_DIM + scol;
    const float* Wp = W + (size_t)(bn * 128 + srow) * K_DIM + scol;
    const int wbase = (srow * 128 + (scol << 1)) ^ ((srow & 7) << 4);

    const int lrow = lane & 15;
    const int lkb  = (lane >> 4) << 3;
    const int fxor = (lrow & 7) << 4;
    const int arow0 = (wm * 64 + lrow) * 128;
    const int brow0 = (wn * 64 + lrow) * 128;

    f32x4 acc[4][4];
#pragma unroll
    for (int m = 0; m < 4; ++m)
#pragma unroll
        for (int n = 0; n < 4; ++n)
            acc[m][n] = (f32x4){0.f, 0.f, 0.f, 0.f};

    float4 areg[8], breg[8];
#pragma unroll
    for (int p = 0; p < 8; ++p) {
        areg[p] = *reinterpret_cast<const float4*>(Ap + (size_t)p * 16 * K_DIM);
        breg[p] = *reinterpret_cast<const float4*>(Wp + (size_t)p * 16 * K_DIM);
    }

    for (int kt = 0; kt < NT; ++kt) {
        __syncthreads();
#pragma unroll
        for (int p = 0; p < 8; ++p) {
            ushort av[4] = {f2bf(areg[p].x), f2bf(areg[p].y),
                            f2bf(areg[p].z), f2bf(areg[p].w)};
            *reinterpret_cast<ushort4*>(sA + (wbase + p * 2048)) =
                *reinterpret_cast<ushort4*>(av);
            ushort bv[4] = {f2bf(breg[p].x), f2bf(breg[p].y),
                            f2bf(breg[p].z), f2bf(breg[p].w)};
            *reinterpret_cast<ushort4*>(sB + (wbase + p * 2048)) =
                *reinterpret_cast<ushort4*>(bv);
        }
        __syncthreads();

        if (kt + 1 < NT) {
            const float* ap = Ap + (size_t)(kt + 1) * BK;
            const float* wp = Wp + (size_t)(kt + 1) * BK;
#pragma unroll
            for (int p = 0; p < 8; ++p) {
                areg[p] = *reinterpret_cast<const float4*>(ap + (size_t)p * 16 * K_DIM);
                breg[p] = *reinterpret_cast<const float4*>(wp + (size_t)p * 16 * K_DIM);
            }
        }

#pragma unroll
        for (int kk = 0; kk < 2; ++kk) {
            const int kcb = (kk * 32 + lkb) * 2;
            bf16x8 af[4], bfv[4];
#pragma unroll
            for (int m = 0; m < 4; ++m)
                af[m] = *reinterpret_cast<const bf16x8*>(
                    sA + ((arow0 + m * 2048 + kcb) ^ fxor));
#pragma unroll
            for (int n = 0; n < 4; ++n)
                bfv[n] = *reinterpret_cast<const bf16x8*>(
                    sB + ((brow0 + n * 2048 + kcb) ^ fxor));
#pragma unroll
            for (int m = 0; m < 4; ++m)
#pragma unroll
                for (int n = 0; n < 4; ++n)
                    acc[m][n] = __builtin_amdgcn_mfma_f32_16x16x32_bf16(
                        af[m], bfv[n], acc[m][n], 0, 0, 0);
        }
    }

    const size_t crow = (size_t)(bm * 128 + wm * 64 + ((lane >> 4) << 2));
    const int    ccol = bn * 128 + wn * 64 + (lane & 15);
    float* Cp = C + crow * N_DIM + ccol;
#pragma unroll
    for (int m = 0; m < 4; ++m)
#pragma unroll
        for (int j = 0; j < 4; ++j) {
            float* cr = Cp + (size_t)(m * 16 + j) * N_DIM;
#pragma unroll
            for (int n = 0; n < 4; ++n)
                cr[n * 16] = acc[m][n][j];
        }
}

extern "C" void kernel_launch(void* const* d_in, const int* in_sizes, int n_in,
                              void* d_out, int out_size, void* d_ws, size_t ws_size,
                              hipStream_t stream) {
    const float* A  = (const float*)d_in[0];   // [8,4096,2048] fp32
    const float* Wt = (const float*)d_in[1];   // [2048,2048] fp32
    float* C = (float*)d_out;                  // [32768,2048] fp32

    const size_t needA = (size_t)M_DIM * K_DIM * 2;
    const size_t needW = (size_t)N_DIM * K_DIM * 2;

    if (ws_size >= needA + needW) {
        ushort* Abf = (ushort*)d_ws;
        ushort* Wbf = (ushort*)((char*)d_ws + needA);
        cvt_f32_bf16<<<dim3(2048), dim3(256), 0, stream>>>(A, Abf, (M_DIM * K_DIM) / 8);
        cvt_f32_bf16<<<dim3(2048), dim3(256), 0, stream>>>(Wt, Wbf, (N_DIM * K_DIM) / 8);
        agmm_8phase<<<dim3(NWG), dim3(512), 0, stream>>>(Abf, Wbf, C);
    } else {
        agmm_fused<<<dim3((M_DIM / 128) * (N_DIM / 128)), dim3(256), 0, stream>>>(A, Wt, C);
    }
}